// Round 8
// baseline (779.698 us; speedup 1.0000x reference)
//
#include <hip/hip_runtime.h>
#include <hip/hip_fp16.h>

#define N_ROWS 32768
#define KCODES 8192
#define CDIM   256
#define NSUB   (KCODES / 16)     // 512 subtiles of 16 codes
#define MARGIN 4.0e-4f           // conservative certified need ~2.9e-4; keep slack
#define LSTR   64                // LDS row stride in bf16 units (XOR swizzle, no pad)

typedef __attribute__((ext_vector_type(8))) short bf16x8;
typedef __attribute__((ext_vector_type(4))) float f32x4;
typedef __attribute__((ext_vector_type(2))) _Float16 h2_t;

typedef const __attribute__((address_space(1))) unsigned int guint_t;
typedef __attribute__((address_space(3))) unsigned int luint_t;

__device__ __forceinline__ void load_lds16(const void* g, void* l) {
    __builtin_amdgcn_global_load_lds((guint_t*)g, (luint_t*)l, 16, 0, 0);
}

__device__ __forceinline__ ushort f2bf_rne(float f) {
    unsigned u = __float_as_uint(f);
    u += 0x7fffu + ((u >> 16) & 1u);
    return (ushort)(u >> 16);
}

// one DPP min step on a packed half2 (row_shr pattern; result accumulates toward lane 15)
template <int CTRL>
__device__ __forceinline__ uint dpp_min_step(uint u) {
    uint s = (uint)__builtin_amdgcn_update_dpp((int)u, (int)u, CTRL, 0xf, 0xf, false);
    h2_t a = __builtin_bit_cast(h2_t, u);
    h2_t b = __builtin_bit_cast(h2_t, s);
    return __builtin_bit_cast(uint, __builtin_elementwise_min(a, b));
}

__device__ __forceinline__ uint row16_min(uint u) {
    u = dpp_min_step<0x111>(u);   // row_shr:1
    u = dpp_min_step<0x112>(u);   // row_shr:2
    u = dpp_min_step<0x114>(u);   // row_shr:4
    u = dpp_min_step<0x118>(u);   // row_shr:8  -> lane 15 of each 16-group holds min
    return u;
}

// ---------- phase 0: fused fp32->bf16 convert + row sum-of-squares for BOTH inputs ----------
__global__ void prep_kernel(const float* __restrict__ x, const float* __restrict__ wgt,
                            ushort* __restrict__ xb, ushort* __restrict__ wb,
                            float* __restrict__ t1, float* __restrict__ e2) {
    int wave = (blockIdx.x * blockDim.x + threadIdx.x) >> 6;
    int lane = threadIdx.x & 63;
    const float* src; ushort* bdst; float* sqdst; int row;
    if (wave < N_ROWS) { src = x; bdst = xb; sqdst = t1; row = wave; }
    else               { src = wgt; bdst = wb; sqdst = e2; row = wave - N_ROWS; }
    float4 v = *((const float4*)src + (size_t)row * (CDIM / 4) + lane);
    ushort4 o;
    o.x = f2bf_rne(v.x); o.y = f2bf_rne(v.y); o.z = f2bf_rne(v.z); o.w = f2bf_rne(v.w);
    *((ushort4*)bdst + (size_t)row * (CDIM / 4) + lane) = o;
    float s = v.x * v.x + v.y * v.y + v.z * v.z + v.w * v.w;
    for (int off = 32; off; off >>= 1) s += __shfl_down(s, off, 64);
    if (lane == 0) sqdst[row] = s;
}

// ---------- phase 1: DMA-staged bf16 MFMA, source-side XOR swizzle, DPP min epilogue ----------
// block tile: 256 rows x 128 codes; 4 waves in 2x2; wave tile: 128 rows x 64 codes
// LDS slot c of row r holds global 16B-chunk (c ^ (r&7)); global_load_lds writes base+lane*16
// which with lane=(r%8)*8+c is exactly linear -> swizzle applied on the SOURCE address.
__launch_bounds__(256, 3)
__global__ void vq_mfma_kernel(const ushort* __restrict__ xb, const ushort* __restrict__ wb,
                               const float* __restrict__ e2, __half* __restrict__ minT) {
    __shared__ ushort xs[256 * LSTR];   // 32 KB ; mbT aliased here after the K loop
    __shared__ ushort ws_l[128 * LSTR]; // 16 KB

    const int t = threadIdx.x;
    const int w = t >> 6, lane = t & 63;
    const int ln15 = lane & 15, quad = lane >> 4;
    const int rt = blockIdx.x >> 6;     // 128 row tiles (64 consecutive blocks share X tile)
    const int ct = blockIdx.x & 63;     // 64 code tiles
    const int rbase = (w >> 1) * 128;   // wave row base (0 or 128)
    const int cbase = (w & 1) * 64;     // wave code base (0 or 64)

    // staging: thread t covers rows (t>>3)+32j; fetches global chunk ((t&7) ^ (row&7))
    const int srow = t >> 3;
    const int schunk = (t & 7) ^ (srow & 7);
    const ushort* xsrc = xb + (size_t)(rt * 256 + srow) * CDIM + schunk * 8;
    const ushort* wsrc = wb + (size_t)(ct * 128 + srow) * CDIM + schunk * 8;
    ushort* xdst = &xs[(size_t)((w * 8) * LSTR)];      // wave-uniform LDS base
    ushort* wdst = &ws_l[(size_t)((w * 8) * LSTR)];

    f32x4 acc[8][4];
#pragma unroll
    for (int mi = 0; mi < 8; ++mi)
#pragma unroll
        for (int ni = 0; ni < 4; ++ni)
#pragma unroll
            for (int r = 0; r < 4; ++r) acc[mi][ni][r] = 0.f;

    for (int cc = 0; cc < 4; ++cc) {                  // K chunks of 64
        __syncthreads();                              // prior readers done
#pragma unroll
        for (int j = 0; j < 8; ++j)
            load_lds16(xsrc + (size_t)j * 32 * CDIM + cc * 64, xdst + j * 32 * LSTR);
#pragma unroll
        for (int j = 0; j < 4; ++j)
            load_lds16(wsrc + (size_t)j * 32 * CDIM + cc * 64, wdst + j * 32 * LSTR);
        __syncthreads();                              // drains vmcnt (DMA complete)
#pragma unroll
        for (int kk = 0; kk < 2; ++kk) {              // two k=32 MFMA steps per chunk
            const int swzA = (((kk * 4 + quad) ^ (ln15 & 7)) * 8);
            bf16x8 a[8], b[4];
#pragma unroll
            for (int mi = 0; mi < 8; ++mi)
                a[mi] = *(const bf16x8*)&xs[(rbase + mi * 16 + ln15) * LSTR + swzA];
#pragma unroll
            for (int ni = 0; ni < 4; ++ni)
                b[ni] = *(const bf16x8*)&ws_l[(cbase + ni * 16 + ln15) * LSTR + swzA];
#pragma unroll
            for (int mi = 0; mi < 8; ++mi)
#pragma unroll
                for (int ni = 0; ni < 4; ++ni)
                    acc[mi][ni] = __builtin_amdgcn_mfma_f32_16x16x32_bf16(a[mi], b[ni], acc[mi][ni], 0, 0, 0);
        }
    }

    // epilogue: r~ = e2 - 2s; packed-half DPP min across the 16 codes of each subtile
    float e2v[4];
#pragma unroll
    for (int ni = 0; ni < 4; ++ni) e2v[ni] = e2[ct * 128 + cbase + ni * 16 + ln15];

    __syncthreads();                                  // xs now dead -> reuse as mbT
    ushort (*mbT)[264] = (ushort (*)[264])xs;

#pragma unroll
    for (int mi = 0; mi < 8; ++mi)
#pragma unroll
        for (int ni = 0; ni < 4; ++ni) {
            float r0 = e2v[ni] - 2.0f * acc[mi][ni][0];
            float r1 = e2v[ni] - 2.0f * acc[mi][ni][1];
            float r2 = e2v[ni] - 2.0f * acc[mi][ni][2];
            float r3 = e2v[ni] - 2.0f * acc[mi][ni][3];
            uint u01 = __builtin_bit_cast(uint, __builtin_amdgcn_cvt_pkrtz(r0, r1));
            uint u23 = __builtin_bit_cast(uint, __builtin_amdgcn_cvt_pkrtz(r2, r3));
            u01 = row16_min(u01);
            u23 = row16_min(u23);
            if (ln15 == 15) {
                int rowb = rbase + mi * 16 + quad * 4;     // rows rowb..rowb+3 (C/D layout)
                int sb   = (cbase >> 4) + ni;
                *(uint*)&mbT[sb][rowb]     = u01;          // rows rowb, rowb+1
                *(uint*)&mbT[sb][rowb + 2] = u23;          // rows rowb+2, rowb+3
            }
        }
    __syncthreads();
    {
        union { ushort s[8]; uint4 u; } r;
#pragma unroll
        for (int s = 0; s < 8; ++s) r.s[s] = mbT[s][t];
        *(uint4*)(minT + (size_t)(rt * 256 + t) * NSUB + ct * 8) = r.u;
    }
}

// ---------- phase 2: exact fp32 re-rank, ONE QUAD (16 lanes) PER ROW + fused gather ----------
__launch_bounds__(256, 4)
__global__ void vq_rerank_kernel(const float* __restrict__ x, const float* __restrict__ wgt,
                                 const float* __restrict__ t1, const float* __restrict__ e2,
                                 const __half* __restrict__ minT,
                                 float* __restrict__ out_q, float* __restrict__ out_i) {
    __shared__ float xrow[16][260];     // 16 rows x 1KB (+16B pad)
    __shared__ int cnt[16];
    __shared__ int lists[16][32];

    const int t = threadIdx.x, w = t >> 6, lane = t & 63;
    const int q = lane >> 4, i = lane & 15;   // quad, lane-in-quad
    const int r = w * 4 + q;                  // local row 0..15
    const int row = blockIdx.x * 16 + r;

    if (t < 16) cnt[t] = 0;
    // stage 16 x-rows (each thread: 4 float4 of row t>>4)
    {
        int sr = t >> 4, sc = t & 15;
        const float4* xp = (const float4*)(x + (size_t)(blockIdx.x * 16 + sr) * CDIM);
#pragma unroll
        for (int k2 = 0; k2 < 4; ++k2)
            *(float4*)&xrow[sr][(sc + 16 * k2) * 4] = xp[sc + 16 * k2];
    }
    __syncthreads();

    // scan this row's 512 subtile minima: lane i covers subtiles i*32 .. i*32+31
    const ushort* mrow = (const ushort*)(minT + (size_t)row * NSUB) + i * 32;
    uint4 raw[4];
#pragma unroll
    for (int k2 = 0; k2 < 4; ++k2) raw[k2] = *((const uint4*)mrow + k2);

    float lmin = 3.402823466e38f;
#pragma unroll
    for (int k2 = 0; k2 < 4; ++k2) {
        const uint* u = (const uint*)&raw[k2];
#pragma unroll
        for (int h = 0; h < 4; ++h) {
            float2 f = __half22float2(__builtin_bit_cast(__half2, u[h]));
            lmin = fminf(lmin, fminf(f.x, f.y));
        }
    }
#pragma unroll
    for (int off = 1; off < 16; off <<= 1) lmin = fminf(lmin, __shfl_xor(lmin, off, 16));
    const float thresh = lmin + MARGIN;

    // build candidate list (unordered; final reduce tie-breaks on smallest k = np argmin rule)
#pragma unroll
    for (int k2 = 0; k2 < 4; ++k2) {
        const uint* u = (const uint*)&raw[k2];
#pragma unroll
        for (int h = 0; h < 4; ++h) {
            float2 f = __half22float2(__builtin_bit_cast(__half2, u[h]));
            int sb = i * 32 + k2 * 8 + h * 2;
            if (f.x <= thresh) { int p = atomicAdd(&cnt[r], 1); if (p < 32) lists[r][p] = sb; }
            if (f.y <= thresh) { int p = atomicAdd(&cnt[r], 1); if (p < 32) lists[r][p] = sb + 1; }
        }
    }
    __syncthreads();

    const float t1r = t1[row];
    int nc = cnt[r]; if (nc > 32) nc = 32;
    float best = 3.402823466e38f;
    int bestk = 0x7fffffff;
    for (int p = 0; p < nc; ++p) {
        int st = lists[r][p];
        int k = st * 16 + i;
        // EXACT round-1 accumulation order: sequential c = 0..255, fmaf chain (bit-identical)
        float acc = 0.f;
        const float4* wp = (const float4*)(wgt + (size_t)k * CDIM);
#pragma unroll
        for (int c4 = 0; c4 < 64; ++c4) {
            float4 wv = wp[c4];
            float4 xv = *(const float4*)&xrow[r][c4 * 4];
            acc = fmaf(xv.x, wv.x, acc);
            acc = fmaf(xv.y, wv.y, acc);
            acc = fmaf(xv.z, wv.z, acc);
            acc = fmaf(xv.w, wv.w, acc);
        }
        float d = (t1r + e2[k]) - 2.0f * acc;   // same quantization chain as np / round 1
        if (d < best || (d == best && k < bestk)) { best = d; bestk = k; }
    }
    // quad-reduce (d, k) with smallest-index tie-break
#pragma unroll
    for (int off = 1; off < 16; off <<= 1) {
        float od = __shfl_xor(best, off, 16);
        int ok = __shfl_xor(bestk, off, 16);
        if (od < best || (od == best && ok < bestk)) { best = od; bestk = ok; }
    }

    // fused gather + index write (quad-wide)
    const float4* src = (const float4*)(wgt + (size_t)bestk * CDIM);
    float4* dst = (float4*)(out_q + (size_t)row * CDIM);
#pragma unroll
    for (int k2 = 0; k2 < 4; ++k2) dst[i + 16 * k2] = src[i + 16 * k2];
    if (i == 0) out_i[row] = (float)bestk;
}

extern "C" void kernel_launch(void* const* d_in, const int* in_sizes, int n_in,
                              void* d_out, int out_size, void* d_ws, size_t ws_size,
                              hipStream_t stream) {
    const float* x = (const float*)d_in[0];   // (8,4096,256) fp32
    const float* wgt = (const float*)d_in[1]; // (8192,256) fp32

    float* out_q = (float*)d_out;
    float* out_i = out_q + (size_t)N_ROWS * CDIM;

    // workspace carve (all 16B aligned): e2, t1, minT, xb, wb  -> ~52.3 MB
    char* p = (char*)d_ws;
    float* e2 = (float*)p;               p += (size_t)KCODES * 4;
    float* t1 = (float*)p;               p += (size_t)N_ROWS * 4;
    __half* minT = (__half*)p;           p += (size_t)N_ROWS * NSUB * 2;
    ushort* xb = (ushort*)p;             p += (size_t)N_ROWS * CDIM * 2;
    ushort* wb = (ushort*)p;             p += (size_t)KCODES * CDIM * 2;

    prep_kernel<<<(N_ROWS + KCODES) / 4, 256, 0, stream>>>(x, wgt, xb, wb, t1, e2);

    vq_mfma_kernel<<<(N_ROWS / 256) * (KCODES / 128), 256, 0, stream>>>(xb, wb, e2, minT);
    vq_rerank_kernel<<<N_ROWS / 16, 256, 0, stream>>>(x, wgt, t1, e2, minT, out_q, out_i);
}

// Round 9
// 585.453 us; speedup vs baseline: 1.3318x; 1.3318x over previous
//
#include <hip/hip_runtime.h>
#include <hip/hip_fp16.h>

#define N_ROWS 32768
#define KCODES 8192
#define CDIM   256
#define NSUB   (KCODES / 16)     // 512 subtiles of 16 codes
#define MARGIN 4.0e-4f           // certified need ~2e-4; 2x slack
#define LSTR   64                // LDS row stride in bf16 units (XOR swizzle, no pad)

typedef __attribute__((ext_vector_type(8))) short bf16x8;
typedef __attribute__((ext_vector_type(4))) float f32x4;

__device__ __forceinline__ ushort f2bf_rne(float f) {
    unsigned u = __float_as_uint(f);
    u += 0x7fffu + ((u >> 16) & 1u);
    return (ushort)(u >> 16);
}

// fp32 min-rotate within each 16-lane row via DPP row_ror (VALU-only, no LDS pipe)
template <int CTRL>
__device__ __forceinline__ float dpp_fmin_step(float v) {
    int s = __builtin_amdgcn_update_dpp(0, __float_as_int(v), CTRL, 0xf, 0xf, true);
    return fminf(v, __int_as_float(s));
}
__device__ __forceinline__ float ror16_min(float v) {
    v = dpp_fmin_step<0x121>(v);   // row_ror:1
    v = dpp_fmin_step<0x122>(v);   // row_ror:2
    v = dpp_fmin_step<0x124>(v);   // row_ror:4
    v = dpp_fmin_step<0x128>(v);   // row_ror:8 -> all 16 lanes hold the min
    return v;
}

// ---------- phase 0: fused fp32->bf16 convert + row sum-of-squares for BOTH inputs ----------
__global__ void prep_kernel(const float* __restrict__ x, const float* __restrict__ wgt,
                            ushort* __restrict__ xb, ushort* __restrict__ wb,
                            float* __restrict__ t1, float* __restrict__ e2) {
    int wave = (blockIdx.x * blockDim.x + threadIdx.x) >> 6;
    int lane = threadIdx.x & 63;
    const float* src; ushort* bdst; float* sqdst; int row;
    if (wave < N_ROWS) { src = x; bdst = xb; sqdst = t1; row = wave; }
    else               { src = wgt; bdst = wb; sqdst = e2; row = wave - N_ROWS; }
    float4 v = *((const float4*)src + (size_t)row * (CDIM / 4) + lane);
    ushort4 o;
    o.x = f2bf_rne(v.x); o.y = f2bf_rne(v.y); o.z = f2bf_rne(v.z); o.w = f2bf_rne(v.w);
    *((ushort4*)bdst + (size_t)row * (CDIM / 4) + lane) = o;
    float s = v.x * v.x + v.y * v.y + v.z * v.z + v.w * v.w;
    for (int off = 32; off; off >>= 1) s += __shfl_down(s, off, 64);
    if (lane == 0) sqdst[row] = s;
}

// ---------- phase 1: LDS-staged bf16 MFMA; epilogue emits (mask | fp16 min) per subtile ----------
// block tile: 256 rows x 128 codes; 4 waves in 2x2; wave tile: 128 rows x 64 codes
// minU[row][sb] = (mask16 of codes with r <= subtile_min + MARGIN) << 16 | fp16(subtile_min)
__launch_bounds__(256, 3)
__global__ void vq_mfma_kernel(const ushort* __restrict__ xb, const ushort* __restrict__ wb,
                               const float* __restrict__ e2, uint* __restrict__ minU) {
    __shared__ ushort xs[256 * LSTR];   // 32 KB ; mbU aliased here after the K loop
    __shared__ ushort ws_l[128 * LSTR]; // 16 KB

    const int t = threadIdx.x;
    const int w = t >> 6, lane = t & 63;
    const int ln15 = lane & 15, quad = lane >> 4;
    const int rt = blockIdx.x >> 6;     // 128 row tiles (64 consecutive blocks share X tile)
    const int ct = blockIdx.x & 63;     // 64 code tiles
    const int rbase = (w >> 1) * 128;   // wave row base (0 or 128)
    const int cbase = (w & 1) * 64;     // wave code base (0 or 64)

    // staging geometry: thread t covers rows (t>>3)+j*32, swizzled 16B chunk
    const int srow = t >> 3, schunk = t & 7;
    const int sswz = (schunk ^ (srow & 7)) * 8;
    const ushort* xsrc = xb + (size_t)(rt * 256 + srow) * CDIM + schunk * 8;
    const ushort* wsrc = wb + (size_t)(ct * 128 + srow) * CDIM + schunk * 8;
    ushort* xdst = &xs[srow * LSTR + sswz];
    ushort* wdst = &ws_l[srow * LSTR + sswz];

    f32x4 acc[8][4];
#pragma unroll
    for (int mi = 0; mi < 8; ++mi)
#pragma unroll
        for (int ni = 0; ni < 4; ++ni)
#pragma unroll
            for (int r = 0; r < 4; ++r) acc[mi][ni][r] = 0.f;

    for (int cc = 0; cc < 4; ++cc) {                  // K chunks of 64
        __syncthreads();
#pragma unroll
        for (int j = 0; j < 8; ++j) {                 // load->store (no long reg holds)
            uint4 v = *(const uint4*)(xsrc + (size_t)j * 32 * CDIM + cc * 64);
            *(uint4*)(xdst + j * 32 * LSTR) = v;
        }
#pragma unroll
        for (int j = 0; j < 4; ++j) {
            uint4 v = *(const uint4*)(wsrc + (size_t)j * 32 * CDIM + cc * 64);
            *(uint4*)(wdst + j * 32 * LSTR) = v;
        }
        __syncthreads();
#pragma unroll
        for (int kk = 0; kk < 2; ++kk) {              // two k=32 MFMA steps per chunk
            const int swzA = (((kk * 4 + quad) ^ (ln15 & 7)) * 8);
            bf16x8 a[8], b[4];
#pragma unroll
            for (int mi = 0; mi < 8; ++mi)
                a[mi] = *(const bf16x8*)&xs[(rbase + mi * 16 + ln15) * LSTR + swzA];
#pragma unroll
            for (int ni = 0; ni < 4; ++ni)
                b[ni] = *(const bf16x8*)&ws_l[(cbase + ni * 16 + ln15) * LSTR + swzA];
#pragma unroll
            for (int mi = 0; mi < 8; ++mi)
#pragma unroll
                for (int ni = 0; ni < 4; ++ni)
                    acc[mi][ni] = __builtin_amdgcn_mfma_f32_16x16x32_bf16(a[mi], b[ni], acc[mi][ni], 0, 0, 0);
        }
    }

    // epilogue: per (row, subtile): fp32 min over 16 codes + mask of codes within MARGIN
    float e2v[4];
#pragma unroll
    for (int ni = 0; ni < 4; ++ni) e2v[ni] = e2[ct * 128 + cbase + ni * 16 + ln15];

    __syncthreads();                                  // xs dead -> alias as mbU
    uint (*mbU)[258] = (uint (*)[258])xs;             // [subtile][row], ~8.3 KB

#pragma unroll
    for (int mi = 0; mi < 8; ++mi)
#pragma unroll
        for (int ni = 0; ni < 4; ++ni)
#pragma unroll
            for (int reg = 0; reg < 4; ++reg) {
                float r = e2v[ni] - 2.0f * acc[mi][ni][reg];
                float m = ror16_min(r);               // all 16 lanes hold subtile min
                unsigned long long b = __ballot(r <= m + MARGIN);
                uint mask = (uint)((b >> (quad * 16)) & 0xffffull);
                if (ln15 == 0) {
                    uint mh = __builtin_bit_cast(uint, __builtin_amdgcn_cvt_pkrtz(m, m)) & 0xffffu;
                    int rowb = rbase + mi * 16 + quad * 4 + reg;   // C/D layout row
                    mbU[(cbase >> 4) + ni][rowb] = (mask << 16) | mh;
                }
            }
    __syncthreads();
    {
        uint4 a, b2;
        a.x = mbU[0][t]; a.y = mbU[1][t]; a.z = mbU[2][t]; a.w = mbU[3][t];
        b2.x = mbU[4][t]; b2.y = mbU[5][t]; b2.z = mbU[6][t]; b2.w = mbU[7][t];
        uint* rowp = minU + (size_t)(rt * 256 + t) * NSUB + ct * 8;
        *(uint4*)rowp = a;
        *(uint4*)(rowp + 4) = b2;
    }
}

// ---------- phase 2: exact fp32 re-rank of CODE-level candidates, wave per row ----------
__launch_bounds__(256, 4)
__global__ void vq_rerank_kernel(const float* __restrict__ x, const float* __restrict__ wgt,
                                 const float* __restrict__ t1, const float* __restrict__ e2,
                                 const uint* __restrict__ minU,
                                 float* __restrict__ out_q, float* __restrict__ out_i) {
    __shared__ float xrow[4][260];
    __shared__ int nlist[4];
    __shared__ int klist[4][128];

    const int t = threadIdx.x, w = t >> 6, lane = t & 63;
    const int row = blockIdx.x * 4 + w;

    if (lane == 0) nlist[w] = 0;
    // stage x row (1 KB) into LDS (wave-local; no cross-wave sync needed)
    *(float4*)&xrow[w][lane * 4] = *((const float4*)(x + (size_t)row * CDIM) + lane);

    // scan 512 packed (mask|min) entries: 8 per lane
    const uint* mrow = minU + (size_t)row * NSUB + lane * 8;
    uint4 r0 = *(const uint4*)mrow;
    uint4 r1 = *(const uint4*)(mrow + 4);
    uint uv[8] = {r0.x, r0.y, r0.z, r0.w, r1.x, r1.y, r1.z, r1.w};
    float m[8];
#pragma unroll
    for (int j = 0; j < 8; ++j)
        m[j] = __half2float(__builtin_bit_cast(__half, (ushort)(uv[j] & 0xffffu)));
    float lmin = m[0];
#pragma unroll
    for (int j = 1; j < 8; ++j) lmin = fminf(lmin, m[j]);
#pragma unroll
    for (int off = 1; off < 64; off <<= 1) lmin = fminf(lmin, __shfl_xor(lmin, off, 64));
    const float thresh = lmin + MARGIN;

    // code-level candidates from masks of in-threshold subtiles
#pragma unroll
    for (int j = 0; j < 8; ++j) {
        if (m[j] <= thresh) {
            uint bm = uv[j] >> 16;
            int kb = (lane * 8 + j) * 16;
            while (bm) {
                int bit = __ffs(bm) - 1;
                bm &= bm - 1;
                int pos = atomicAdd(&nlist[w], 1);
                if (pos < 128) klist[w][pos] = kb + bit;
            }
        }
    }
    int nc = nlist[w]; if (nc > 128) nc = 128;

    const float t1r = t1[row];
    float best = 3.402823466e38f;
    int bestk = 0x7fffffff;
    for (int p0 = 0; p0 < nc; p0 += 64) {
        int li = p0 + lane;
        float d = 3.402823466e38f;
        int k = 0x7fffffff;
        if (li < nc) {
            k = klist[w][li];
            // EXACT round-1 accumulation order: sequential c = 0..255, fmaf chain
            float acc = 0.f;
            const float4* wp = (const float4*)(wgt + (size_t)k * CDIM);
#pragma unroll
            for (int c4 = 0; c4 < 64; ++c4) {
                float4 wv = wp[c4];
                float4 xv = *(const float4*)&xrow[w][c4 * 4];
                acc = fmaf(xv.x, wv.x, acc);
                acc = fmaf(xv.y, wv.y, acc);
                acc = fmaf(xv.z, wv.z, acc);
                acc = fmaf(xv.w, wv.w, acc);
            }
            d = (t1r + e2[k]) - 2.0f * acc;    // same quantization chain as np / round 1
        }
        if (d < best || (d == best && k < bestk)) { best = d; bestk = k; }
    }
    // wave-reduce (d, k) with smallest-index tie-break (np argmin semantics)
#pragma unroll
    for (int off = 1; off < 64; off <<= 1) {
        float od = __shfl_xor(best, off, 64);
        int ok = __shfl_xor(bestk, off, 64);
        if (od < best || (od == best && ok < bestk)) { best = od; bestk = ok; }
    }

    // fused gather + index write
    const float4* src = (const float4*)(wgt + (size_t)bestk * CDIM);
    ((float4*)(out_q + (size_t)row * CDIM))[lane] = src[lane];
    if (lane == 0) out_i[row] = (float)bestk;
}

extern "C" void kernel_launch(void* const* d_in, const int* in_sizes, int n_in,
                              void* d_out, int out_size, void* d_ws, size_t ws_size,
                              hipStream_t stream) {
    const float* x = (const float*)d_in[0];   // (8,4096,256) fp32
    const float* wgt = (const float*)d_in[1]; // (8192,256) fp32

    float* out_q = (float*)d_out;
    float* out_i = out_q + (size_t)N_ROWS * CDIM;

    // workspace carve (16B aligned): e2, t1, minU(64MB), xb, wb -> ~84.4 MB
    char* p = (char*)d_ws;
    float* e2 = (float*)p;               p += (size_t)KCODES * 4;
    float* t1 = (float*)p;               p += (size_t)N_ROWS * 4;
    uint* minU = (uint*)p;               p += (size_t)N_ROWS * NSUB * 4;
    ushort* xb = (ushort*)p;             p += (size_t)N_ROWS * CDIM * 2;
    ushort* wb = (ushort*)p;             p += (size_t)KCODES * CDIM * 2;

    prep_kernel<<<(N_ROWS + KCODES) / 4, 256, 0, stream>>>(x, wgt, xb, wb, t1, e2);

    vq_mfma_kernel<<<(N_ROWS / 256) * (KCODES / 128), 256, 0, stream>>>(xb, wb, e2, minU);
    vq_rerank_kernel<<<N_ROWS / 4, 256, 0, stream>>>(x, wgt, t1, e2, minU, out_q, out_i);
}

// Round 10
// 433.541 us; speedup vs baseline: 1.7984x; 1.3504x over previous
//
#include <hip/hip_runtime.h>
#include <hip/hip_fp16.h>

#define N_ROWS 32768
#define KCODES 8192
#define CDIM   256
#define NSUB   (KCODES / 16)     // 512 subtiles of 16 codes
#define MARGIN 4.0e-4f           // certified need ~2e-4; 2x slack
#define LSTR   64                // LDS row stride in bf16 units (XOR swizzle, no pad)

typedef __attribute__((ext_vector_type(8))) short bf16x8;
typedef __attribute__((ext_vector_type(4))) float f32x4;

__device__ __forceinline__ ushort f2bf_rne(float f) {
    unsigned u = __float_as_uint(f);
    u += 0x7fffu + ((u >> 16) & 1u);
    return (ushort)(u >> 16);
}

// fp32 min-rotate within each 16-lane row via DPP row_ror (VALU-only, no LDS pipe)
template <int CTRL>
__device__ __forceinline__ float dpp_fmin_step(float v) {
    int s = __builtin_amdgcn_update_dpp(0, __float_as_int(v), CTRL, 0xf, 0xf, true);
    return fminf(v, __int_as_float(s));
}
__device__ __forceinline__ float ror16_min(float v) {
    v = dpp_fmin_step<0x121>(v);   // row_ror:1
    v = dpp_fmin_step<0x122>(v);   // row_ror:2
    v = dpp_fmin_step<0x124>(v);   // row_ror:4
    v = dpp_fmin_step<0x128>(v);   // row_ror:8 -> all 16 lanes hold the min
    return v;
}

// ---------- phase 0: fused fp32->bf16 convert + row sum-of-squares for BOTH inputs ----------
__global__ void prep_kernel(const float* __restrict__ x, const float* __restrict__ wgt,
                            ushort* __restrict__ xb, ushort* __restrict__ wb,
                            float* __restrict__ t1, float* __restrict__ e2) {
    int wave = (blockIdx.x * blockDim.x + threadIdx.x) >> 6;
    int lane = threadIdx.x & 63;
    const float* src; ushort* bdst; float* sqdst; int row;
    if (wave < N_ROWS) { src = x; bdst = xb; sqdst = t1; row = wave; }
    else               { src = wgt; bdst = wb; sqdst = e2; row = wave - N_ROWS; }
    float4 v = *((const float4*)src + (size_t)row * (CDIM / 4) + lane);
    ushort4 o;
    o.x = f2bf_rne(v.x); o.y = f2bf_rne(v.y); o.z = f2bf_rne(v.z); o.w = f2bf_rne(v.w);
    *((ushort4*)bdst + (size_t)row * (CDIM / 4) + lane) = o;
    float s = v.x * v.x + v.y * v.y + v.z * v.z + v.w * v.w;
    for (int off = 32; off; off >>= 1) s += __shfl_down(s, off, 64);
    if (lane == 0) sqdst[row] = s;
}

// ---------- phase 1: LDS-staged bf16 MFMA (round-7 structure); mask|min epilogue ----------
// block tile: 256 rows x 128 codes; 4 waves in 2x2; wave tile: 128 rows x 64 codes
// NOTE: 112 VGPR + 128 acc regs -> MUST stay at 2 waves/EU; (256,3) spills accs (round-9 regression)
__launch_bounds__(256, 2)
__global__ void vq_mfma_kernel(const ushort* __restrict__ xb, const ushort* __restrict__ wb,
                               const float* __restrict__ e2, uint* __restrict__ minU) {
    __shared__ ushort xs[256 * LSTR];   // 32 KB ; mbU aliased here after the K loop
    __shared__ ushort ws_l[128 * LSTR]; // 16 KB

    const int t = threadIdx.x;
    const int w = t >> 6, lane = t & 63;
    const int ln15 = lane & 15, quad = lane >> 4;
    const int rt = blockIdx.x >> 6;     // 128 row tiles (64 consecutive blocks share X tile)
    const int ct = blockIdx.x & 63;     // 64 code tiles
    const int rbase = (w >> 1) * 128;   // wave row base (0 or 128)
    const int cbase = (w & 1) * 64;     // wave code base (0 or 64)

    // staging geometry: thread t covers rows (t>>3)+j*32, swizzled 16B chunk
    const int srow = t >> 3, schunk = t & 7;
    const int sswz = (schunk ^ (srow & 7)) * 8;
    const ushort* xsrc = xb + (size_t)(rt * 256 + srow) * CDIM + schunk * 8;
    const ushort* wsrc = wb + (size_t)(ct * 128 + srow) * CDIM + schunk * 8;
    ushort* xdst = &xs[srow * LSTR + sswz];
    ushort* wdst = &ws_l[srow * LSTR + sswz];

    f32x4 acc[8][4];
#pragma unroll
    for (int mi = 0; mi < 8; ++mi)
#pragma unroll
        for (int ni = 0; ni < 4; ++ni)
#pragma unroll
            for (int r = 0; r < 4; ++r) acc[mi][ni][r] = 0.f;

    for (int cc = 0; cc < 4; ++cc) {                  // K chunks of 64
        __syncthreads();                              // prior readers done
#pragma unroll
        for (int j = 0; j < 8; ++j) {                 // load->store (no long reg holds)
            uint4 v = *(const uint4*)(xsrc + (size_t)j * 32 * CDIM + cc * 64);
            *(uint4*)(xdst + j * 32 * LSTR) = v;
        }
#pragma unroll
        for (int j = 0; j < 4; ++j) {
            uint4 v = *(const uint4*)(wsrc + (size_t)j * 32 * CDIM + cc * 64);
            *(uint4*)(wdst + j * 32 * LSTR) = v;
        }
        __syncthreads();
#pragma unroll
        for (int kk = 0; kk < 2; ++kk) {              // two k=32 MFMA steps per chunk
            const int swzA = (((kk * 4 + quad) ^ (ln15 & 7)) * 8);
            bf16x8 a[8], b[4];
#pragma unroll
            for (int mi = 0; mi < 8; ++mi)
                a[mi] = *(const bf16x8*)&xs[(rbase + mi * 16 + ln15) * LSTR + swzA];
#pragma unroll
            for (int ni = 0; ni < 4; ++ni)
                b[ni] = *(const bf16x8*)&ws_l[(cbase + ni * 16 + ln15) * LSTR + swzA];
#pragma unroll
            for (int mi = 0; mi < 8; ++mi)
#pragma unroll
                for (int ni = 0; ni < 4; ++ni)
                    acc[mi][ni] = __builtin_amdgcn_mfma_f32_16x16x32_bf16(a[mi], b[ni], acc[mi][ni], 0, 0, 0);
        }
    }

    // epilogue: per (row, subtile): fp32 min over 16 codes + mask of codes within MARGIN
    float e2v[4];
#pragma unroll
    for (int ni = 0; ni < 4; ++ni) e2v[ni] = e2[ct * 128 + cbase + ni * 16 + ln15];

    __syncthreads();                                  // xs dead -> alias as mbU
    uint (*mbU)[258] = (uint (*)[258])xs;             // [subtile][row], ~8.3 KB

#pragma unroll
    for (int mi = 0; mi < 8; ++mi)
#pragma unroll
        for (int ni = 0; ni < 4; ++ni)
#pragma unroll
            for (int reg = 0; reg < 4; ++reg) {
                float r = e2v[ni] - 2.0f * acc[mi][ni][reg];
                float m = ror16_min(r);               // all 16 lanes hold subtile min
                unsigned long long b = __ballot(r <= m + MARGIN);
                uint mask = (uint)((b >> (quad * 16)) & 0xffffull);
                if (ln15 == 0) {
                    uint mh = __builtin_bit_cast(uint, __builtin_amdgcn_cvt_pkrtz(m, m)) & 0xffffu;
                    int rowb = rbase + mi * 16 + quad * 4 + reg;   // C/D layout row
                    mbU[(cbase >> 4) + ni][rowb] = (mask << 16) | mh;
                }
            }
    __syncthreads();
    {
        uint4 a, b2;
        a.x = mbU[0][t]; a.y = mbU[1][t]; a.z = mbU[2][t]; a.w = mbU[3][t];
        b2.x = mbU[4][t]; b2.y = mbU[5][t]; b2.z = mbU[6][t]; b2.w = mbU[7][t];
        uint* rowp = minU + (size_t)(rt * 256 + t) * NSUB + ct * 8;
        *(uint4*)rowp = a;
        *(uint4*)(rowp + 4) = b2;
    }
}

// ---------- phase 2: exact fp32 re-rank of CODE-level candidates, wave per row ----------
__launch_bounds__(256, 4)
__global__ void vq_rerank_kernel(const float* __restrict__ x, const float* __restrict__ wgt,
                                 const float* __restrict__ t1, const float* __restrict__ e2,
                                 const uint* __restrict__ minU,
                                 float* __restrict__ out_q, float* __restrict__ out_i) {
    __shared__ float xrow[4][260];
    __shared__ int nlist[4];
    __shared__ int klist[4][128];

    const int t = threadIdx.x, w = t >> 6, lane = t & 63;
    const int row = blockIdx.x * 4 + w;

    if (lane == 0) nlist[w] = 0;
    // stage x row (1 KB) into LDS (wave-local; no cross-wave sync needed)
    *(float4*)&xrow[w][lane * 4] = *((const float4*)(x + (size_t)row * CDIM) + lane);

    // scan 512 packed (mask|min) entries: 8 per lane
    const uint* mrow = minU + (size_t)row * NSUB + lane * 8;
    uint4 r0 = *(const uint4*)mrow;
    uint4 r1 = *(const uint4*)(mrow + 4);
    uint uv[8] = {r0.x, r0.y, r0.z, r0.w, r1.x, r1.y, r1.z, r1.w};
    float m[8];
#pragma unroll
    for (int j = 0; j < 8; ++j)
        m[j] = __half2float(__builtin_bit_cast(__half, (ushort)(uv[j] & 0xffffu)));
    float lmin = m[0];
#pragma unroll
    for (int j = 1; j < 8; ++j) lmin = fminf(lmin, m[j]);
#pragma unroll
    for (int off = 1; off < 64; off <<= 1) lmin = fminf(lmin, __shfl_xor(lmin, off, 64));
    const float thresh = lmin + MARGIN;

    // code-level candidates from masks of in-threshold subtiles
#pragma unroll
    for (int j = 0; j < 8; ++j) {
        if (m[j] <= thresh) {
            uint bm = uv[j] >> 16;
            int kb = (lane * 8 + j) * 16;
            while (bm) {
                int bit = __ffs(bm) - 1;
                bm &= bm - 1;
                int pos = atomicAdd(&nlist[w], 1);
                if (pos < 128) klist[w][pos] = kb + bit;
            }
        }
    }
    int nc = nlist[w]; if (nc > 128) nc = 128;

    const float t1r = t1[row];
    float best = 3.402823466e38f;
    int bestk = 0x7fffffff;
    for (int p0 = 0; p0 < nc; p0 += 64) {
        int li = p0 + lane;
        float d = 3.402823466e38f;
        int k = 0x7fffffff;
        if (li < nc) {
            k = klist[w][li];
            // EXACT round-1 accumulation order: sequential c = 0..255, fmaf chain
            float acc = 0.f;
            const float4* wp = (const float4*)(wgt + (size_t)k * CDIM);
#pragma unroll
            for (int c4 = 0; c4 < 64; ++c4) {
                float4 wv = wp[c4];
                float4 xv = *(const float4*)&xrow[w][c4 * 4];
                acc = fmaf(xv.x, wv.x, acc);
                acc = fmaf(xv.y, wv.y, acc);
                acc = fmaf(xv.z, wv.z, acc);
                acc = fmaf(xv.w, wv.w, acc);
            }
            d = (t1r + e2[k]) - 2.0f * acc;    // same quantization chain as np / round 1
        }
        if (d < best || (d == best && k < bestk)) { best = d; bestk = k; }
    }
    // wave-reduce (d, k) with smallest-index tie-break (np argmin semantics)
#pragma unroll
    for (int off = 1; off < 64; off <<= 1) {
        float od = __shfl_xor(best, off, 64);
        int ok = __shfl_xor(bestk, off, 64);
        if (od < best || (od == best && ok < bestk)) { best = od; bestk = ok; }
    }

    // fused gather + index write
    const float4* src = (const float4*)(wgt + (size_t)bestk * CDIM);
    ((float4*)(out_q + (size_t)row * CDIM))[lane] = src[lane];
    if (lane == 0) out_i[row] = (float)bestk;
}

extern "C" void kernel_launch(void* const* d_in, const int* in_sizes, int n_in,
                              void* d_out, int out_size, void* d_ws, size_t ws_size,
                              hipStream_t stream) {
    const float* x = (const float*)d_in[0];   // (8,4096,256) fp32
    const float* wgt = (const float*)d_in[1]; // (8192,256) fp32

    float* out_q = (float*)d_out;
    float* out_i = out_q + (size_t)N_ROWS * CDIM;

    // workspace carve (16B aligned): e2, t1, minU(67MB), xb, wb -> ~84.4 MB
    char* p = (char*)d_ws;
    float* e2 = (float*)p;               p += (size_t)KCODES * 4;
    float* t1 = (float*)p;               p += (size_t)N_ROWS * 4;
    uint* minU = (uint*)p;               p += (size_t)N_ROWS * NSUB * 4;
    ushort* xb = (ushort*)p;             p += (size_t)N_ROWS * CDIM * 2;
    ushort* wb = (ushort*)p;             p += (size_t)KCODES * CDIM * 2;

    prep_kernel<<<(N_ROWS + KCODES) / 4, 256, 0, stream>>>(x, wgt, xb, wb, t1, e2);

    vq_mfma_kernel<<<(N_ROWS / 256) * (KCODES / 128), 256, 0, stream>>>(xb, wb, e2, minU);
    vq_rerank_kernel<<<N_ROWS / 4, 256, 0, stream>>>(x, wgt, t1, e2, minU, out_q, out_i);
}